// Round 1
// baseline (557.494 us; speedup 1.0000x reference)
//
#include <hip/hip_runtime.h>
#include <hip/hip_bf16.h>
#include <cstdint>
#include <cstddef>

typedef unsigned short u16;
typedef unsigned int u32;
typedef short bf16x8 __attribute__((ext_vector_type(8)));
typedef float f32x4 __attribute__((ext_vector_type(4)));
typedef float f32x2 __attribute__((ext_vector_type(2)));

static constexpr int Bb = 4, Tt = 2048, Dd = 1024, NFf = 512, NBb = 4;
static constexpr int Mm = Bb * Tt;      // 8192 tokens
static constexpr int NZz = 4864;        // packed projection width (4613 padded to 19*256 for 256-tile GEMM)
static constexpr int Lc = 32;           // conv kernel support (|A|<=0.59 -> 0.59^32 ~ 5e-8)

#define DEV __device__ __forceinline__

typedef const __attribute__((address_space(1))) u32* gas_p;
typedef __attribute__((address_space(3))) u32* las_p;

DEV u16 f2bf(float f) {
    uint32_t u = __float_as_uint(f);
    u = (u + 0x7FFF + ((u >> 16) & 1)) >> 16;   // RNE
    return (u16)u;
}
DEV float bf2f(u16 h) { return __uint_as_float(((uint32_t)h) << 16); }
DEV float sigm(float x) { return 1.0f / (1.0f + __expf(-x)); }
DEV float gelu_ex(float t) { return 0.5f * t * (1.0f + erff(t * 0.70710678118f)); }

// ---------------------------------------------------------------- prep_all: freq consts + weight cvt + LN1
static constexpr int NW0 = NZz * Dd;        // wcat
static constexpr int NW1 = Dd * 2 * NFf;    // wfs
static constexpr int NW2 = 4 * Dd * Dd;     // w1
static constexpr int NW3 = 4 * Dd * Dd;     // w2
static constexpr int NWTOT = NW0 + NW1 + NW2 + NW3;
static constexpr int NWB = NWTOT / 256;     // weight blocks

__global__ __launch_bounds__(256) void prep_all(
    const float* __restrict__ Wconcept, const float* __restrict__ Wcg,
    const float* __restrict__ Wfg, const float* __restrict__ Wgate,
    const float* __restrict__ Wsp, const float* __restrict__ Wtg,
    const float* __restrict__ Wband,
    const float* __restrict__ bconcept, const float* __restrict__ bcg,
    const float* __restrict__ bfg, const float* __restrict__ bgate,
    const float* __restrict__ btg, const float* __restrict__ bband,
    const float* __restrict__ Wfs, const float* __restrict__ W1,
    const float* __restrict__ W2,
    const float* __restrict__ fi, const float* __restrict__ logd,
    const float* __restrict__ freqs, const float* __restrict__ dtv,
    const float* __restrict__ x, const float* __restrict__ norm_g,
    const float* __restrict__ norm_b,
    u16* __restrict__ wcat, float* __restrict__ bias_cat,
    u16* __restrict__ wfs, u16* __restrict__ w1b, u16* __restrict__ w2b,
    float* __restrict__ rr, float* __restrict__ ri,
    float* __restrict__ Ar, float* __restrict__ Ai,
    u16* __restrict__ xn)
{
    const int bx = blockIdx.x;
    if (bx == 0) {
        __shared__ float red[256];
        int t = threadIdx.x;
        float v0 = fi[t], v1 = fi[t + 256];
        red[t] = fmaxf(v0, v1); __syncthreads();
        for (int s = 128; s; s >>= 1) { if (t < s) red[t] = fmaxf(red[t], red[t + s]); __syncthreads(); }
        float mx = red[0]; __syncthreads();
        float e0 = expf(v0 - mx), e1 = expf(v1 - mx);
        red[t] = e0 + e1; __syncthreads();
        for (int s = 128; s; s >>= 1) { if (t < s) red[t] += red[t + s]; __syncthreads(); }
        float inv = 1.0f / red[0];
#pragma unroll
        for (int k = 0; k < 2; k++) {
            int f = t + k * 256;
            float e = k ? e1 : e0;
            float decay = sigm(logd[f]) * (e * inv * (float)NFf);
            float omega = freqs[f] * 0.1f * (sigm(dtv[f]) * 2.0f);
            float cc = cosf(omega), ss = sinf(omega);
            rr[f] = cc; ri[f] = ss; Ar[f] = decay * cc; Ai[f] = decay * ss;
        }
        return;
    }
    if (bx <= NWB) {
        int i = (bx - 1) * 256 + threadIdx.x;
        if (i < NW0) {
            int r = i >> 10, c = i & 1023;
            float v;
            if      (r < 1024) v = Wconcept[r * 1024 + c];
            else if (r < 2048) v = Wcg[(r - 1024) * 1024 + c];
            else if (r < 2560) v = Wfg[(r - 2048) * 1024 + c];
            else if (r < 3584) v = Wgate[(r - 2560) * 1024 + c];
            else if (r < 4608) v = Wsp[(r - 3584) * 1024 + c];
            else if (r == 4608) v = Wtg[c];
            else if (r < 4613) v = Wband[(r - 4609) * 1024 + c];
            else v = 0.0f;
            wcat[i] = f2bf(v);
            if (c == 0) {
                float bv;
                if      (r < 1024) bv = bconcept[r];
                else if (r < 2048) bv = bcg[r - 1024];
                else if (r < 2560) bv = bfg[r - 2048];
                else if (r < 3584) bv = bgate[r - 2560];
                else if (r < 4608) bv = 0.0f;
                else if (r == 4608) bv = btg[0];
                else if (r < 4613) bv = bband[r - 4609];
                else bv = 0.0f;
                bias_cat[r] = bv;
            }
        } else if (i < NW0 + NW1) {
            int j = i - NW0; wfs[j] = f2bf(Wfs[j]);
        } else if (i < NW0 + NW1 + NW2) {
            int j = i - NW0 - NW1; w1b[j] = f2bf(W1[j]);
        } else {
            int j = i - NW0 - NW1 - NW2; w2b[j] = f2bf(W2[j]);
        }
        return;
    }
    // LN1 role: one block per token row
    const int m = bx - NWB - 1, tid = threadIdx.x;
    float4 v = ((const float4*)(x + (size_t)m * Dd))[tid];
    float s1 = v.x + v.y + v.z + v.w;
    float s2 = v.x * v.x + v.y * v.y + v.z * v.z + v.w * v.w;
    __shared__ float lds[16];
    for (int o = 32; o; o >>= 1) { s1 += __shfl_down(s1, o); s2 += __shfl_down(s2, o); }
    int lane = tid & 63, w = tid >> 6;
    if (!lane) { lds[w] = s1; lds[8 + w] = s2; }
    __syncthreads();
    s1 = lds[0] + lds[1] + lds[2] + lds[3];
    s2 = lds[8] + lds[9] + lds[10] + lds[11];
    float mean = s1 * (1.0f / Dd);
    float var  = s2 * (1.0f / Dd) - mean * mean;
    float rstd = rsqrtf(var + 1e-5f);
    float4 gv = ((const float4*)norm_g)[tid];
    float4 bv = ((const float4*)norm_b)[tid];
    ushort4 o;
    o.x = f2bf((v.x - mean) * rstd * gv.x + bv.x);
    o.y = f2bf((v.y - mean) * rstd * gv.y + bv.y);
    o.z = f2bf((v.z - mean) * rstd * gv.z + bv.z);
    o.w = f2bf((v.w - mean) * rstd * gv.w + bv.w);
    ((ushort4*)(xn + (size_t)m * Dd))[tid] = o;
}

// ---------------------------------------------------------------- 128^2 GEMM (bf16 MFMA, BK=64, xor-swizzled LDS)
// MODE 4: bf16 = acc      MODE 3: f32 = acc + bias[n] + bf2f(addb[m,n])
template<int MODE>
__global__ __launch_bounds__(256, 3) void gemm_bt(
    const u16* __restrict__ A, const u16* __restrict__ Bw,
    const float* __restrict__ bias, const u16* __restrict__ addb,
    void* __restrict__ Cout, int M, int N, int K)
{
    __shared__ __align__(16) u16 smA[128 * 64];   // 16 KB
    __shared__ __align__(16) u16 smB[128 * 64];   // 16 KB
    const int tid = threadIdx.x;
    const int m0 = blockIdx.x * 128;
    const int n0 = blockIdx.y * 128;
    const int w = tid >> 6, lane = tid & 63;
    const int wr = w >> 1, wc = w & 1;
    const int quad = lane >> 4, l16 = lane & 15;

    const int r0 = tid >> 3;                       // 0..31
    const int cs = (tid & 7) ^ (r0 & 7);
    const u16* gA = A + (size_t)(m0 + r0) * K + cs * 8;
    const u16* gB = Bw + (size_t)(n0 + r0) * K + cs * 8;

    const int swzf = l16 & 7;                      // fragment-read swizzle (row&7)

    f32x4 acc[4][4];
#pragma unroll
    for (int i = 0; i < 4; i++)
#pragma unroll
        for (int j = 0; j < 4; j++) acc[i][j] = {0.f, 0.f, 0.f, 0.f};

    for (int k0 = 0; k0 < K; k0 += 64) {
        __syncthreads();
#pragma unroll
        for (int j = 0; j < 4; j++) {
            __builtin_amdgcn_global_load_lds((gas_p)(gA + k0 + (size_t)(j * 32) * K),
                                             (las_p)(smA + j * 2048 + tid * 8), 16, 0, 0);
            __builtin_amdgcn_global_load_lds((gas_p)(gB + k0 + (size_t)(j * 32) * K),
                                             (las_p)(smB + j * 2048 + tid * 8), 16, 0, 0);
        }
        __syncthreads();
#pragma unroll
        for (int seg = 0; seg < 2; seg++) {
            bf16x8 af[4], bfv[4];
#pragma unroll
            for (int mi = 0; mi < 4; mi++)
                af[mi] = *(const bf16x8*)&smA[(wr * 64 + mi * 16 + l16) * 64 +
                                              (((seg * 4 + quad) ^ swzf) * 8)];
#pragma unroll
            for (int ni = 0; ni < 4; ni++)
                bfv[ni] = *(const bf16x8*)&smB[(wc * 64 + ni * 16 + l16) * 64 +
                                               (((seg * 4 + quad) ^ swzf) * 8)];
#pragma unroll
            for (int mi = 0; mi < 4; mi++)
#pragma unroll
                for (int ni = 0; ni < 4; ni++)
                    acc[mi][ni] = __builtin_amdgcn_mfma_f32_16x16x32_bf16(
                        af[mi], bfv[ni], acc[mi][ni], 0, 0, 0);
        }
    }

#pragma unroll
    for (int mi = 0; mi < 4; mi++) {
#pragma unroll
        for (int ni = 0; ni < 4; ni++) {
            const int gn = n0 + wc * 64 + ni * 16 + l16;
            const int gm0 = m0 + wr * 64 + mi * 16 + quad * 4;
            if constexpr (MODE == 4) {
                float t0 = acc[mi][ni][0], t1 = acc[mi][ni][1];
                float t2 = acc[mi][ni][2], t3 = acc[mi][ni][3];
                __hip_bfloat162 h01 = __float22bfloat162_rn(float2{t0, t1});
                __hip_bfloat162 h23 = __float22bfloat162_rn(float2{t2, t3});
                __hip_bfloat16* o = (__hip_bfloat16*)Cout;
                o[(size_t)(gm0 + 0) * N + gn] = h01.x;
                o[(size_t)(gm0 + 1) * N + gn] = h01.y;
                o[(size_t)(gm0 + 2) * N + gn] = h23.x;
                o[(size_t)(gm0 + 3) * N + gn] = h23.y;
            } else {
#pragma unroll
                for (int r = 0; r < 4; r++) {
                    const int gm = gm0 + r;
                    ((float*)Cout)[(size_t)gm * N + gn] =
                        acc[mi][ni][r] + bias[gn] + bf2f(addb[(size_t)gm * N + gn]);
                }
            }
        }
    }
}

// ---------------------------------------------------------------- 256^2 8-phase GEMM (T2+T3+T4+T5)
// 512 thr / 8 waves (2x4), BK=64, dbuf LDS 128 KiB, counted vmcnt(4)/K-tile.
// Phases = C-quadrants (qa,qb): P0=(0,0) P1=(0,1) P2=(1,0) P3=(1,1).
// Prefetch: P0->(t+1)A-h1, P1->(t+1)B-h1 (other buffer); P2->(t+2)A-h0, P3->(t+2)B-h0
// (same buffer — A-h0/B-h0 dead after P0: only P0 reads them from LDS).
// MODE 0: bf16 = acc + bias[n]   MODE 2: bf16 = gelu(acc + bias[n])
template<int MODE>
__global__ __launch_bounds__(512, 2) void gemm_bt256(
    const u16* __restrict__ A, const u16* __restrict__ Bw,
    const float* __restrict__ bias,
    void* __restrict__ Cout, int M, int N, int K)
{
    __shared__ __align__(16) u16 smA[2][256 * 64];   // 64 KB
    __shared__ __align__(16) u16 smB[2][256 * 64];   // 64 KB
    const int tid = threadIdx.x;
    const int m0 = blockIdx.x * 256;
    const int n0 = blockIdx.y * 256;
    const int w = tid >> 6, lane = tid & 63;
    const int wr = w >> 2, wc = w & 3;               // 2 x 4 wave grid
    const int quad = lane >> 4, l16 = lane & 15;
    const int swzf = l16 & 7;

    // staging: thread t -> row (t>>3) within 64-row group, chunk (t&7)^(row&7)
    const int rs = tid >> 3;                          // 0..63
    const int cs = (tid & 7) ^ (rs & 7);
    const u16* gA = A + (size_t)(m0 + rs) * K + cs * 8;
    const u16* gB = Bw + (size_t)(n0 + rs) * K + cs * 8;

    f32x4 acc[2][2][4][2];
#pragma unroll
    for (int qa = 0; qa < 2; qa++)
#pragma unroll
        for (int qb = 0; qb < 2; qb++)
#pragma unroll
            for (int mi = 0; mi < 4; mi++)
#pragma unroll
                for (int ni = 0; ni < 2; ni++) acc[qa][qb][mi][ni] = {0.f, 0.f, 0.f, 0.f};

    bf16x8 af[4][2], bf0[2][2], bf1[2][2];

#define STG_A(BUF, H, KO) do { \
    __builtin_amdgcn_global_load_lds((gas_p)(gA + (size_t)((H) * 128) * K + (KO)), \
        (las_p)(&smA[BUF][(H) * 128 * 64 + tid * 8]), 16, 0, 0); \
    __builtin_amdgcn_global_load_lds((gas_p)(gA + (size_t)((H) * 128 + 64) * K + (KO)), \
        (las_p)(&smA[BUF][((H) * 128 + 64) * 64 + tid * 8]), 16, 0, 0); \
} while (0)
#define STG_B(BUF, H, KO) do { \
    __builtin_amdgcn_global_load_lds((gas_p)(gB + (size_t)((H) * 128) * K + (KO)), \
        (las_p)(&smB[BUF][(H) * 128 * 64 + tid * 8]), 16, 0, 0); \
    __builtin_amdgcn_global_load_lds((gas_p)(gB + (size_t)((H) * 128 + 64) * K + (KO)), \
        (las_p)(&smB[BUF][((H) * 128 + 64) * 64 + tid * 8]), 16, 0, 0); \
} while (0)
#define LOAD_AF(QA) do { \
    _Pragma("unroll") for (int mi = 0; mi < 4; mi++) \
    _Pragma("unroll") for (int kk = 0; kk < 2; kk++) \
        af[mi][kk] = *(const bf16x8*)&smA[cur][((QA) * 128 + wr * 64 + mi * 16 + l16) * 64 + \
                                              (((kk * 4 + quad) ^ swzf) * 8)]; \
} while (0)
#define LOAD_BF(QB, BF) do { \
    _Pragma("unroll") for (int ni = 0; ni < 2; ni++) \
    _Pragma("unroll") for (int kk = 0; kk < 2; kk++) \
        BF[ni][kk] = *(const bf16x8*)&smB[cur][((QB) * 128 + wc * 32 + ni * 16 + l16) * 64 + \
                                               (((kk * 4 + quad) ^ swzf) * 8)]; \
} while (0)
#define MFMA16(QA, QB, BF) do { \
    _Pragma("unroll") for (int mi = 0; mi < 4; mi++) \
    _Pragma("unroll") for (int ni = 0; ni < 2; ni++) \
    _Pragma("unroll") for (int kk = 0; kk < 2; kk++) \
        acc[QA][QB][mi][ni] = __builtin_amdgcn_mfma_f32_16x16x32_bf16( \
            af[mi][kk], BF[ni][kk], acc[QA][QB][mi][ni], 0, 0, 0); \
} while (0)

    const int NT = K >> 6;
    // prologue: tile0 all 4 halves -> buf0; tile1 A-h0,B-h0 -> buf1 (steady-state invariant)
    STG_A(0, 0, 0); STG_A(0, 1, 0);
    STG_B(0, 0, 0); STG_B(0, 1, 0);
    STG_A(1, 0, 64); STG_B(1, 0, 64);
    asm volatile("s_waitcnt vmcnt(4)" ::: "memory");  // tile0 landed, tile1-h0s in flight
    __builtin_amdgcn_s_barrier();
    asm volatile("" ::: "memory");

    for (int t = 0; t < NT; ++t) {
        const int cur = t & 1, nxt = cur ^ 1;
        const int kn1 = (t + 1) << 6, kn2 = (t + 2) << 6;
        const bool i1 = (t + 1) < NT, i2 = (t + 2) < NT;
        // ---- P0 (qa0,qb0): reads A-h0,B-h0 (their ONLY LDS reads this tile)
        LOAD_AF(0);
        LOAD_BF(0, bf0);
        if (i1) STG_A(nxt, 1, kn1);
        __builtin_amdgcn_s_barrier();
        asm volatile("s_waitcnt lgkmcnt(0)" ::: "memory");
        __builtin_amdgcn_s_setprio(1);
        MFMA16(0, 0, bf0);
        __builtin_amdgcn_s_setprio(0);
        __builtin_amdgcn_s_barrier();
        // ---- P1 (qa0,qb1): reads B-h1 (reuses af)
        LOAD_BF(1, bf1);
        if (i1) STG_B(nxt, 1, kn1);
        __builtin_amdgcn_s_barrier();
        asm volatile("s_waitcnt lgkmcnt(0)" ::: "memory");
        __builtin_amdgcn_s_setprio(1);
        MFMA16(0, 1, bf1);
        __builtin_amdgcn_s_setprio(0);
        __builtin_amdgcn_s_barrier();
        // ---- P2 (qa1,qb0): reads A-h1 (reuses bf0); A-h0 now dead -> prefetch t+2 A-h0
        LOAD_AF(1);
        if (i2) STG_A(cur, 0, kn2);
        __builtin_amdgcn_s_barrier();
        asm volatile("s_waitcnt lgkmcnt(0)" ::: "memory");
        __builtin_amdgcn_s_setprio(1);
        MFMA16(1, 0, bf0);
        __builtin_amdgcn_s_setprio(0);
        __builtin_amdgcn_s_barrier();
        // ---- P3 (qa1,qb1): no LDS reads (reuses af,bf1); B-h0 dead -> prefetch t+2 B-h0
        if (i2) STG_B(cur, 0, kn2);
        __builtin_amdgcn_s_barrier();
        __builtin_amdgcn_s_setprio(1);
        MFMA16(1, 1, bf1);
        __builtin_amdgcn_s_setprio(0);
        // ---- tile boundary: counted drain (keeps t+2 h0s in flight), never 0 mid-loop
        if (i2) asm volatile("s_waitcnt vmcnt(4)" ::: "memory");
        else    asm volatile("s_waitcnt vmcnt(0)" ::: "memory");
        __builtin_amdgcn_s_barrier();
        asm volatile("" ::: "memory");
    }

#undef STG_A
#undef STG_B
#undef LOAD_AF
#undef LOAD_BF
#undef MFMA16

#pragma unroll
    for (int qa = 0; qa < 2; qa++)
#pragma unroll
    for (int qb = 0; qb < 2; qb++)
#pragma unroll
    for (int mi = 0; mi < 4; mi++)
#pragma unroll
    for (int ni = 0; ni < 2; ni++) {
        const int gn = n0 + qb * 128 + wc * 32 + ni * 16 + l16;
        const int gm0 = m0 + qa * 128 + wr * 64 + mi * 16 + quad * 4;
        const float bv = bias[gn];
        float t0 = acc[qa][qb][mi][ni][0] + bv, t1 = acc[qa][qb][mi][ni][1] + bv;
        float t2 = acc[qa][qb][mi][ni][2] + bv, t3 = acc[qa][qb][mi][ni][3] + bv;
        if constexpr (MODE == 2) {
            t0 = gelu_ex(t0); t1 = gelu_ex(t1); t2 = gelu_ex(t2); t3 = gelu_ex(t3);
        }
        __hip_bfloat162 h01 = __float22bfloat162_rn(float2{t0, t1});
        __hip_bfloat162 h23 = __float22bfloat162_rn(float2{t2, t3});
        __hip_bfloat16* o = (__hip_bfloat16*)Cout;
        o[(size_t)(gm0 + 0) * N + gn] = h01.x;
        o[(size_t)(gm0 + 1) * N + gn] = h01.y;
        o[(size_t)(gm0 + 2) * N + gn] = h23.x;
        o[(size_t)(gm0 + 3) * N + gn] = h23.y;
    }
}

// ---------------------------------------------------------------- prepAk: u2b = (sp)*sigmoid(fg) (bf16x2) + k2 recurrence
static constexpr int NBLK_A = (Mm * NFf) / 256;   // 16384

__global__ __launch_bounds__(256) void prepAk_kernel(
    const u16* __restrict__ Z, ushort2* __restrict__ u2b,
    const float* __restrict__ Ar, const float* __restrict__ Ai,
    const float* __restrict__ rr, const float* __restrict__ ri,
    f32x2* __restrict__ k2)
{
    const int bx = blockIdx.x;
    if (bx < NBLK_A) {
        int i = bx * 256 + threadIdx.x;
        int m = i >> 9, f = i & (NFf - 1);
        const u16* zr = Z + (size_t)m * NZz;
        float fg  = sigm(bf2f(zr[2048 + f]));
        float spr = bf2f(zr[3584 + f]);
        float spi = bf2f(zr[3584 + NFf + f]);
        u2b[i] = ushort2{f2bf(spr * fg), f2bf(spi * fg)};
        return;
    }
    int g = (bx - NBLK_A) * 256 + threadIdx.x;
    int b = g >> 9, f = g & (NFf - 1);
    float Pr = 1.0f, Pi = 0.0f;
    float ar = Ar[f], ai = Ai[f], cr = rr[f], ci = ri[f];
    const int band = f >> 7;          // NFf/NBb = 128
    const u16* zb = Z + (size_t)(b * Tt) * NZz;
    for (int tau = 0; tau < Lc; tau++) {
        const u16* zrow = zb + (size_t)tau * NZz;
        float tsv = sigm(bf2f(zrow[4608]));
        k2[((size_t)b * Lc + tau) * NFf + f] = f32x2{tsv * (cr * Pr - ci * Pi),
                                                     tsv * (cr * Pi + ci * Pr)};
        float bsv = sigm(bf2f(zrow[4609 + band]));
        float er = ar * bsv, ei = ai * bsv;
        float nPr = Pr * er - Pi * ei;
        float nPi = Pr * ei + Pi * er;
        Pr = nPr; Pi = nPi;
    }
}

// ---------------------------------------------------------------- conv: LDS tile + register sliding window
__global__ __launch_bounds__(256) void conv_kernel(
    const ushort2* __restrict__ u2b, const f32x2* __restrict__ k2,
    u16* __restrict__ spec)
{
    __shared__ f32x2 su[96 * 64];     // u rows t0-32 .. t0+63
    __shared__ f32x2 sk[Lc * 64];
    const int tid = threadIdx.x;
    const int fl = tid & 63;
    const int ty = tid >> 6;          // 0..3
    const int f0 = blockIdx.x * 64;
    const int t0 = blockIdx.y * 64;
    const int b  = blockIdx.z;

    for (int i = tid; i < Lc * 64; i += 256) {
        int tau = i >> 6, ff = i & 63;
        sk[i] = k2[((size_t)b * Lc + tau) * NFf + f0 + ff];
    }
    for (int i = tid; i < 96 * 64; i += 256) {
        int r = i >> 6, ff = i & 63;
        int t = t0 - 32 + r;
        f32x2 v = {0.f, 0.f};
        if (t >= 0) {
            ushort2 h = u2b[((size_t)b * Tt + t) * NFf + f0 + ff];
            v = f32x2{bf2f(h.x), bf2f(h.y)};
        }
        su[i] = v;
    }
    __syncthreads();

    const int tl0 = 32 + ty * 16;
    f32x2 win[16], y[16];
#pragma unroll
    for (int j = 0; j < 16; j++) {
        win[j] = su[(tl0 + j) * 64 + fl];
        y[j] = f32x2{0.f, 0.f};
    }
#pragma unroll
    for (int tau = 0; tau < Lc; tau++) {
        f32x2 k = sk[tau * 64 + fl];
#pragma unroll
        for (int j = 0; j < 16; j++) {
            y[j].x += win[j].x * k.x - win[j].y * k.y;
            y[j].y += win[j].x * k.y + win[j].y * k.x;
        }
#pragma unroll
        for (int j = 15; j >= 1; j--) win[j] = win[j - 1];
        win[0] = su[(tl0 - tau - 1) * 64 + fl];   // >= row 0 always
    }
#pragma unroll
    for (int j = 0; j < 16; j++) {
        size_t row = (size_t)(b * Tt + t0 + ty * 16 + j);
        spec[row * (2 * NFf) + f0 + fl]       = f2bf(y[j].x);
        spec[row * (2 * NFf) + NFf + f0 + fl] = f2bf(y[j].y);
    }
}

// ---------------------------------------------------------------- x2 = x + 0.5*(P2*os*gate + concept*cg) (bf16); xn2 = LN2(x2)
__global__ __launch_bounds__(256) void fuse2_ln_kernel(
    const float* __restrict__ x, const u16* __restrict__ Z,
    const u16* __restrict__ P2, const float* __restrict__ osc,
    const float* __restrict__ g2, const float* __restrict__ b2v,
    u16* __restrict__ x2b, u16* __restrict__ xn2)
{
    const int m = blockIdx.x, tid = threadIdx.x;
    const float os = osc[0];
    const u16* zr = Z + (size_t)m * NZz;
    float4 xv = ((const float4*)(x + (size_t)m * Dd))[tid];
    ushort4 pv = ((const ushort4*)(P2 + (size_t)m * Dd))[tid];
    float vals[4]; float s1 = 0.0f, s2 = 0.0f;
#pragma unroll
    for (int j = 0; j < 4; j++) {
        int d = tid * 4 + j;
        float concept = bf2f(zr[d]);
        float cg   = sigm(bf2f(zr[1024 + d]));
        float gate = sigm(bf2f(zr[2560 + d]));
        float p = bf2f((&pv.x)[j]);
        float v = (&xv.x)[j] + 0.5f * (p * os * gate + concept * cg);
        vals[j] = v; s1 += v; s2 += v * v;
    }
    __shared__ float lds[16];
    for (int o = 32; o; o >>= 1) { s1 += __shfl_down(s1, o); s2 += __shfl_down(s2, o); }
    int lane = tid & 63, w = tid >> 6;
    if (!lane) { lds[w] = s1; lds[8 + w] = s2; }
    __syncthreads();
    s1 = lds[0] + lds[1] + lds[2] + lds[3];
    s2 = lds[8] + lds[9] + lds[10] + lds[11];
    float mean = s1 * (1.0f / Dd);
    float var  = s2 * (1.0f / Dd) - mean * mean;
    float rstd = rsqrtf(var + 1e-5f);
    ushort4 xo, no;
#pragma unroll
    for (int j = 0; j < 4; j++) {
        int d = tid * 4 + j;
        (&xo.x)[j] = f2bf(vals[j]);
        (&no.x)[j] = f2bf((vals[j] - mean) * rstd * g2[d] + b2v[d]);
    }
    ((ushort4*)(x2b + (size_t)m * Dd))[tid] = xo;
    ((ushort4*)(xn2 + (size_t)m * Dd))[tid] = no;
}

// ---------------------------------------------------------------- launch
extern "C" void kernel_launch(void* const* d_in, const int* in_sizes, int n_in,
                              void* d_out, int out_size, void* d_ws, size_t ws_size,
                              hipStream_t stream)
{
    const float* x        = (const float*)d_in[0];
    const float* norm_g   = (const float*)d_in[1];
    const float* norm_b   = (const float*)d_in[2];
    const float* Wconcept = (const float*)d_in[3];
    const float* bconcept = (const float*)d_in[4];
    const float* Wcg      = (const float*)d_in[5];
    const float* bcg      = (const float*)d_in[6];
    const float* Wfg      = (const float*)d_in[7];
    const float* bfg      = (const float*)d_in[8];
    const float* Wtg      = (const float*)d_in[9];
    const float* btg      = (const float*)d_in[10];
    const float* Wband    = (const float*)d_in[11];
    const float* bband    = (const float*)d_in[12];
    const float* Wsp      = (const float*)d_in[13];
    const float* fi       = (const float*)d_in[14];
    const float* logd     = (const float*)d_in[15];
    const float* freqs    = (const float*)d_in[16];
    const float* dtv      = (const float*)d_in[17];
    const float* Wgate    = (const float*)d_in[18];
    const float* bgate    = (const float*)d_in[19];
    const float* Wfs      = (const float*)d_in[20];
    const float* osc      = (const float*)d_in[21];
    const float* n2g      = (const float*)d_in[22];
    const float* n2b      = (const float*)d_in[23];
    const float* W1       = (const float*)d_in[24];
    const float* b1       = (const float*)d_in[25];
    const float* W2       = (const float*)d_in[26];
    const float* b2       = (const float*)d_in[27];

    char* ws = (char*)d_ws;
    size_t off = 0;
    auto alloc = [&](size_t bytes) { size_t c = off; off += (bytes + 255) & ~(size_t)255; return c; };
    size_t o_wcat = alloc((size_t)NZz * Dd * 2);
    size_t o_bias = alloc((size_t)NZz * 4);
    size_t o_wfs  = alloc((size_t)Dd * 2 * NFf * 2);
    size_t o_w1   = alloc((size_t)4 * Dd * Dd * 2);
    size_t o_w2   = alloc((size_t)4 * Dd * Dd * 2);
    size_t o_xn   = alloc((size_t)Mm * Dd * 2);
    size_t o_Z    = alloc((size_t)Mm * NZz * 2);        // reused for h
    size_t o_u    = alloc((size_t)Mm * NFf * 4);        // u2b (bf16x2); later x2b (bf16)
    size_t o_spec = alloc((size_t)Mm * Dd * 2);         // spectral; later xn2
    size_t o_P2   = alloc((size_t)Mm * Dd * 2);         // y_proj raw (bf16)
    size_t o_k2   = alloc((size_t)Bb * Lc * NFf * 8);
    size_t o_rr   = alloc(NFf * 4);
    size_t o_ri   = alloc(NFf * 4);
    size_t o_Ar   = alloc(NFf * 4);
    size_t o_Ai   = alloc(NFf * 4);
    if (ws_size < off) return;

    u16*    wcat = (u16*)(ws + o_wcat);
    float*  bias = (float*)(ws + o_bias);
    u16*    wfs  = (u16*)(ws + o_wfs);
    u16*    w1b  = (u16*)(ws + o_w1);
    u16*    w2b  = (u16*)(ws + o_w2);
    u16*    xn   = (u16*)(ws + o_xn);
    u16*    Zb   = (u16*)(ws + o_Z);
    u16*    hb   = (u16*)(ws + o_Z);
    ushort2* u2b = (ushort2*)(ws + o_u);
    u16*    x2b  = (u16*)(ws + o_u);      // u2b consumed by conv before fuse2 writes x2b
    u16*    spec = (u16*)(ws + o_spec);
    u16*    xn2  = (u16*)(ws + o_spec);
    u16*    P2   = (u16*)(ws + o_P2);
    f32x2*  k2   = (f32x2*)(ws + o_k2);
    float*  rr   = (float*)(ws + o_rr);
    float*  ri   = (float*)(ws + o_ri);
    float*  Ar   = (float*)(ws + o_Ar);
    float*  Ai   = (float*)(ws + o_Ai);

    // 1) freq consts + all weight conversion + LN1 (single launch)
    prep_all<<<1 + NWB + Mm, 256, 0, stream>>>(
        Wconcept, Wcg, Wfg, Wgate, Wsp, Wtg, Wband,
        bconcept, bcg, bfg, bgate, btg, bband,
        Wfs, W1, W2, fi, logd, freqs, dtv,
        x, norm_g, norm_b,
        wcat, bias, wfs, w1b, w2b, rr, ri, Ar, Ai, xn);

    // 2) fused projection GEMM: Z = xn @ wcat^T + bias  (8192 x 4864, K=1024) — 256^2 8-phase
    gemm_bt256<0><<<dim3(Mm / 256, NZz / 256), 512, 0, stream>>>(
        xn, wcat, bias, (void*)Zb, Mm, NZz, Dd);

    // 3) u2b (bf16) + k2 recurrence (merged)
    prepAk_kernel<<<NBLK_A + (Bb * NFf) / 256, 256, 0, stream>>>(
        Zb, u2b, Ar, Ai, rr, ri, k2);

    // 4) truncated causal convolution (LDS tile + register window) -> spectral_out (bf16)
    conv_kernel<<<dim3(NFf / 64, Tt / 64, Bb), 256, 0, stream>>>(u2b, k2, spec);

    // 5) P2 = spectral @ Wfs^T (bf16 out)  (8192 x 1024, K=2048) — N=1024 keeps 128^2 (grid occupancy)
    gemm_bt<4><<<dim3(Mm / 128, Dd / 128), 256, 0, stream>>>(
        spec, wfs, nullptr, nullptr, (void*)P2, Mm, Dd, 2 * NFf);

    // 6) gate/concept fuse + residual + LN2 (x2 -> bf16)
    fuse2_ln_kernel<<<Mm, 256, 0, stream>>>(x, Zb, P2, osc, n2g, n2b, x2b, xn2);

    // 7) MLP: h = gelu(xn2 @ W1^T + b1) — 256^2 8-phase; out = x2 + h @ W2^T + b2 — 128^2 (N=1024)
    gemm_bt256<2><<<dim3(Mm / 256, (4 * Dd) / 256), 512, 0, stream>>>(
        xn2, w1b, b1, (void*)hb, Mm, 4 * Dd, Dd);
    gemm_bt<3><<<dim3(Mm / 128, Dd / 128), 256, 0, stream>>>(
        hb, w2b, b2, x2b, d_out, Mm, Dd, 4 * Dd);
}